// Round 18
// baseline (720.415 us; speedup 1.0000x reference)
//
#include <hip/hip_runtime.h>
#include <hip/hip_bf16.h>

#define N_NODESC 50000
#define N_EDGESC 800000
#define N_GRAPHSC 512
#define HDIM 64
#define FNODE 32
#define FEDGE 8
#define NCLS 10
#define BN_EPS 1e-5f
#define SCAN_B 256
#define SCAN_G 196  // 196*256 = 50176 >= 50000
#define NPW 8       // nodes per wave in conv (50000 -> 6250 waves)

typedef __bf16 bf16x8 __attribute__((ext_vector_type(8)));
typedef float f32x4 __attribute__((ext_vector_type(4)));
typedef unsigned long long uint64;
typedef unsigned long long u64x2 __attribute__((ext_vector_type(2)));
typedef unsigned int uint32;

static __device__ __forceinline__ float bcast(float v, int k) {
  return __uint_as_float(__builtin_amdgcn_readlane(__float_as_uint(v), k));
}
static __device__ __forceinline__ int bcast_i(int v, int k) {
  return __builtin_amdgcn_readlane(v, k);
}
static __device__ __forceinline__ unsigned short f2bu(float f) {
  __hip_bfloat16 b = __float2bfloat16(f);
  return *reinterpret_cast<unsigned short*>(&b);
}
static __device__ __forceinline__ float bu2f(unsigned short u) {
  __hip_bfloat16 b;
  *reinterpret_cast<unsigned short*>(&b) = u;
  return __bfloat162float(b);
}

// ---------------- degree ----------------
__global__ void k_deg(const int* __restrict__ dst, uint32* __restrict__ degi) {
  int e = blockIdx.x * blockDim.x + threadIdx.x;
  if (e < N_EDGESC) atomicAdd(&degi[dst[e]], 1u);
}

// ---------------- scan1 (+ fused dinv) ----------------
__global__ void k_scan1(const uint32* __restrict__ degi, uint32* __restrict__ ptr,
                        uint32* __restrict__ bsum, float* __restrict__ dinv) {
  __shared__ uint32 s[SCAN_B];
  int t = threadIdx.x;
  int i = blockIdx.x * SCAN_B + t;
  uint32 v = (i < N_NODESC) ? degi[i] : 0u;
  if (i < N_NODESC) dinv[i] = rsqrtf(fmaxf((float)v, 1.0f));
  s[t] = v; __syncthreads();
  for (int off = 1; off < SCAN_B; off <<= 1) {
    uint32 x = (t >= off) ? s[t - off] : 0u; __syncthreads();
    s[t] += x; __syncthreads();
  }
  if (i < N_NODESC) ptr[i] = s[t] - v;  // exclusive local scan
  if (t == SCAN_B - 1) bsum[blockIdx.x] = s[t];
}

__global__ void k_scan2(uint32* __restrict__ bsum) {
  __shared__ uint32 s[256];
  int t = threadIdx.x;
  uint32 v = (t < SCAN_G) ? bsum[t] : 0u;
  s[t] = v; __syncthreads();
  for (int off = 1; off < 256; off <<= 1) {
    uint32 x = (t >= off) ? s[t - off] : 0u; __syncthreads();
    s[t] += x; __syncthreads();
  }
  if (t < SCAN_G) bsum[t] = s[t] - v;  // exclusive
}

__global__ void k_scan3(uint32* __restrict__ ptr, const uint32* __restrict__ bsum) {
  int i = blockIdx.x * SCAN_B + threadIdx.x;
  if (i < N_NODESC) ptr[i] += bsum[blockIdx.x];
  if (blockIdx.x == 0 && threadIdx.x == 0) ptr[N_NODESC] = N_EDGESC;  // CSR sentinel
}

// ---------------- column stats (sum, sumsq) into a slot ----------------
template <int C>
__global__ void k_colstats(const float* __restrict__ in, int nrows, float* __restrict__ stats) {
  const int RPB = 256 / C;
  int tid = threadIdx.x;
  int col = tid % C;
  int rowOff = tid / C;
  float s = 0.f, s2 = 0.f;
  for (int r = blockIdx.x * RPB + rowOff; r < nrows; r += gridDim.x * RPB) {
    float v = in[r * C + col];
    s += v; s2 += v * v;
  }
  __shared__ float ls[256], ls2[256];
  ls[tid] = s; ls2[tid] = s2;
  __syncthreads();
  for (int off = 128; off >= C; off >>= 1) {
    if (tid < off) { ls[tid] += ls[tid + off]; ls2[tid] += ls2[tid + off]; }
    __syncthreads();
  }
  if (tid < C) {
    atomicAdd(&stats[tid], ls[tid]);
    atomicAdd(&stats[C + tid], ls2[tid]);
  }
}

// ---------------- fold BN into weights (from precomputed stats slot) ----------------
template <int CIN, int COUT>
__global__ void k_foldbn(const float* __restrict__ stats, float invN,
                         const float* __restrict__ bnw, const float* __restrict__ bnb,
                         const float* __restrict__ W, const float* __restrict__ bias,
                         float* __restrict__ Wf, float* __restrict__ bf) {
  __shared__ float a[CIN], sh[CIN];
  int tid = threadIdx.x;
  if (tid < CIN) {
    float m = stats[tid] * invN;
    float v = stats[CIN + tid] * invN - m * m;
    float inv = rsqrtf(v + BN_EPS);
    float aa = bnw[tid] * inv;
    a[tid] = aa;
    sh[tid] = bnb[tid] - m * aa;
  }
  __syncthreads();
  for (int i = tid; i < CIN * COUT; i += 256) {
    int r = i / COUT;
    Wf[i] = a[r] * W[i];
  }
  if (tid < COUT) {
    float acc = bias ? bias[tid] : 0.f;
    for (int r = 0; r < CIN; ++r) acc += sh[r] * W[r * COUT + tid];
    bf[tid] = acc;
  }
}

// ---------------- single-block fused stats+fold (small inputs: g, g2) ----------------
template <int C, int COUT>
__global__ void k_statsfold(const float* __restrict__ in, int nrows,
                            const float* __restrict__ bnw, const float* __restrict__ bnb,
                            const float* __restrict__ W, const float* __restrict__ bias,
                            float* __restrict__ Wf, float* __restrict__ bfo) {
  __shared__ float a[C], sh[C];
  __shared__ float ls[256], ls2[256];
  int tid = threadIdx.x;
  const int RPB = 256 / C;
  int col = tid % C;
  int rowOff = tid / C;
  float s = 0.f, s2 = 0.f;
  for (int r = rowOff; r < nrows; r += RPB) {
    float v = in[(size_t)r * C + col];
    s += v; s2 += v * v;
  }
  ls[tid] = s; ls2[tid] = s2;
  __syncthreads();
  for (int off = 128; off >= C; off >>= 1) {
    if (tid < off) { ls[tid] += ls[tid + off]; ls2[tid] += ls2[tid + off]; }
    __syncthreads();
  }
  if (tid < C) {
    float m = ls[tid] / (float)nrows;
    float v = ls2[tid] / (float)nrows - m * m;
    float inv = rsqrtf(v + BN_EPS);
    float aa = bnw[tid] * inv;
    a[tid] = aa;
    sh[tid] = bnb[tid] - m * aa;
  }
  __syncthreads();
  for (int i = tid; i < C * COUT; i += 256) {
    int r = i / COUT;
    Wf[i] = a[r] * W[i];
  }
  if (tid < COUT) {
    float acc = bias ? bias[tid] : 0.f;
    for (int r = 0; r < C; ++r) acc += sh[r] * W[r * COUT + tid];
    bfo[tid] = acc;
  }
}

// ---------------- head matmul: out[N,64] = in @ W + bias, relu ----------------
template <int K, bool RELU>
__global__ void k_nodemm(const float* __restrict__ in, int nrows,
                         const float* __restrict__ W, const float* __restrict__ bias,
                         float* __restrict__ out) {
  int tid = threadIdx.x;
  int lane = tid & 63;
  float w[K];
#pragma unroll
  for (int k = 0; k < K; ++k) w[k] = W[k * 64 + lane];
  float bv = bias ? bias[lane] : 0.f;
  int wave = (blockIdx.x * blockDim.x + tid) >> 6;
  int nwaves = (gridDim.x * blockDim.x) >> 6;
  for (int r = wave; r < nrows; r += nwaves) {
    float rv = (lane < K) ? in[(size_t)r * K + lane] : 0.f;
    float acc = bv;
#pragma unroll
    for (int k = 0; k < K; ++k) acc = fmaf(bcast(rv, k), w[k], acc);
    if (RELU) acc = fmaxf(acc, 0.f);
    out[(size_t)r * 64 + lane] = acc;
  }
}

// ---------------- fused stage0: h0/hA/hB/relu + fused h-stats ----------------
__global__ void __launch_bounds__(256, 2) k_stage0(
    const float* __restrict__ x, int nrows,
    const float* __restrict__ Wf, const float* __restrict__ bfv,
    const float* __restrict__ WA, const float* __restrict__ bA,
    const float* __restrict__ WB,
    float* __restrict__ h, unsigned short* __restrict__ hAb,
    unsigned short* __restrict__ hBb, float* __restrict__ stats) {
  __shared__ float st_s[64], st_s2[64];
  int tid = threadIdx.x;
  int lane = tid & 63;
  if (tid < 64) { st_s[tid] = 0.f; st_s2[tid] = 0.f; }
  __syncthreads();
  float w0[FNODE], wA[64], wB[64];
#pragma unroll
  for (int k = 0; k < FNODE; ++k) w0[k] = Wf[k * 64 + lane];
#pragma unroll
  for (int k = 0; k < 64; ++k) wA[k] = WA[k * 64 + lane];
#pragma unroll
  for (int k = 0; k < 64; ++k) wB[k] = WB[k * 64 + lane];
  float b0 = bfv[lane];
  float b2 = bA[lane];
  int wave = (blockIdx.x * blockDim.x + tid) >> 6;
  int nwaves = (gridDim.x * blockDim.x) >> 6;
  float s = 0.f, s2 = 0.f;
  for (int r = wave; r < nrows; r += nwaves) {
    float xv = (lane < FNODE) ? x[(size_t)r * FNODE + lane] : 0.f;
    float t0 = b0;
#pragma unroll
    for (int k = 0; k < FNODE; ++k) t0 = fmaf(bcast(xv, k), w0[k], t0);  // h0 (pre-relu)
    float aA = b2, aB = 0.f;
#pragma unroll
    for (int k = 0; k < 64; ++k) {
      float tb = bcast(t0, k);
      aA = fmaf(tb, wA[k], aA);
      aB = fmaf(tb, wB[k], aB);
    }
    float hv = fmaxf(t0, 0.f);
    h[(size_t)r * 64 + lane] = hv;
    s += hv; s2 += hv * hv;
    hAb[(size_t)r * 64 + lane] = f2bu(aA);
    hBb[(size_t)r * 64 + lane] = f2bu(aB);
  }
  atomicAdd(&st_s[lane], s);
  atomicAdd(&st_s2[lane], s2);
  __syncthreads();
  if (tid < 64) atomicAdd(&stats[tid], st_s[tid]);
  else if (tid < 128) atomicAdd(&stats[tid], st_s2[tid - 64]);
}

// ---------------- fused per-conv node prep (inline BN fold): ht, htA, htB ----------------
// htP col-PERMUTED (c' = (c&15)*4 + (c>>4)); htBb LINEAR.
__global__ void __launch_bounds__(256, 2) k_node3(
    const float* __restrict__ h, int nrows,
    const float* __restrict__ stats, float invN,
    const float* __restrict__ bnw, const float* __restrict__ bnb,
    const float* __restrict__ Wn_i, const float* __restrict__ Wnb_i,
    const float* __restrict__ WA, const float* __restrict__ Wab,
    const float* __restrict__ WB,
    uint32* __restrict__ htP, unsigned short* __restrict__ htBb) {
  __shared__ float a_s[64], sh_s[64];
  int tid = threadIdx.x;
  int lane = tid & 63;
  if (tid < 64) {
    float m = stats[tid] * invN;
    float v = stats[64 + tid] * invN - m * m;
    float inv = rsqrtf(v + BN_EPS);
    float aa = bnw[tid] * inv;
    a_s[tid] = aa;
    sh_s[tid] = bnb[tid] - m * aa;
  }
  __syncthreads();
  float w1[64], w2[64], w3[64];
  float b1 = Wnb_i[lane];
#pragma unroll
  for (int k = 0; k < 64; ++k) {
    float raw = Wn_i[k * 64 + lane];
    w1[k] = a_s[k] * raw;
    b1 = fmaf(sh_s[k], raw, b1);
  }
#pragma unroll
  for (int k = 0; k < 64; ++k) w2[k] = WA[k * 64 + lane];
#pragma unroll
  for (int k = 0; k < 64; ++k) w3[k] = WB[k * 64 + lane];
  float b2 = Wab[lane];
  int cperm = (lane & 15) * 4 + (lane >> 4);
  int wave = (blockIdx.x * blockDim.x + tid) >> 6;
  int nwaves = (gridDim.x * blockDim.x) >> 6;
  for (int r = wave; r < nrows; r += nwaves) {
    float hv = h[(size_t)r * 64 + lane];
    float t1 = b1;
#pragma unroll
    for (int k = 0; k < 64; ++k) t1 = fmaf(bcast(hv, k), w1[k], t1);  // ht
    float t2 = b2;
    float t3 = 0.f;
#pragma unroll
    for (int k = 0; k < 64; ++k) {
      float tb = bcast(t1, k);
      t2 = fmaf(tb, w2[k], t2);  // htA (+Web)
      t3 = fmaf(tb, w3[k], t3);  // htB
    }
    htP[(size_t)r * 64 + cperm] = ((uint32)f2bu(t2) << 16) | (uint32)f2bu(t1);
    htBb[(size_t)r * 64 + lane] = f2bu(t3);
  }
}

// ---------------- fused scatter + edge-init (8-byte packed edge record) ----------------
// rec u64 = norm_f32 << 32 | (d&7) << 17 | s
__global__ void k_scatedge(
    const int* __restrict__ src, const int* __restrict__ dst,
    const float* __restrict__ ea, const float* __restrict__ dinv,
    const uint32* __restrict__ ptr, uint32* __restrict__ cursor,
    const unsigned short* __restrict__ hAb, const unsigned short* __restrict__ hBb,
    const float* __restrict__ Wc,
    uint64* __restrict__ edge8,
    __hip_bfloat16* __restrict__ ebf) {
  int tid = threadIdx.x;
  int lane = tid & 63;
  float w[FEDGE];
#pragma unroll
  for (int k = 0; k < FEDGE; ++k) w[k] = Wc[k * 64 + lane];
  int wave = (blockIdx.x * blockDim.x + tid) >> 6;
  int nwaves = (gridDim.x * blockDim.x) >> 6;
  const int nquads = N_EDGESC / 4;
  int per = (nquads + nwaves - 1) / nwaves;
  int p0 = wave * per;
  int p1 = min(p0 + per, nquads);
  for (int pr = p0; pr < p1; ++pr) {
    int e = 4 * pr;
    // lanes 0..3 own one edge each
    int sv = (lane < 4) ? src[e + lane] : 0;
    int dv = (lane < 4) ? dst[e + lane] : 0;
    int s_j[4], d_j[4];
#pragma unroll
    for (int j = 0; j < 4; ++j) { s_j[j] = bcast_i(sv, j); d_j[j] = bcast_i(dv, j); }
    uint32 idx_l = 0;
    if (lane < 4) {
      uint32 rk = atomicAdd(&cursor[dv], 1u);
      idx_l = ptr[dv] + rk;
      float nf = dinv[sv] * dinv[dv];
      uint64 rec = ((uint64)__float_as_uint(nf) << 32) |
                   ((uint64)(dv & (NPW - 1)) << 17) | (uint64)(uint32)sv;
      __builtin_nontemporal_store(rec, edge8 + idx_l);
    }
    int i_j[4];
#pragma unroll
    for (int j = 0; j < 4; ++j) i_j[j] = bcast_i((int)idx_l, j);
    // ea for 4 edges: 32 contiguous floats
    float eav = (lane < 32) ? ea[(size_t)e * FEDGE + lane] : 0.f;
    // row gathers
    unsigned short a0 = hAb[(size_t)s_j[0] * 64 + lane], b0 = hBb[(size_t)d_j[0] * 64 + lane];
    unsigned short a1 = hAb[(size_t)s_j[1] * 64 + lane], b1 = hBb[(size_t)d_j[1] * 64 + lane];
    unsigned short a2 = hAb[(size_t)s_j[2] * 64 + lane], b2 = hBb[(size_t)d_j[2] * 64 + lane];
    unsigned short a3 = hAb[(size_t)s_j[3] * 64 + lane], b3 = hBb[(size_t)d_j[3] * 64 + lane];
    float acc0 = bu2f(a0) + bu2f(b0);
    float acc1 = bu2f(a1) + bu2f(b1);
    float acc2 = bu2f(a2) + bu2f(b2);
    float acc3 = bu2f(a3) + bu2f(b3);
#pragma unroll
    for (int k = 0; k < FEDGE; ++k) {
      acc0 = fmaf(bcast(eav, 0 * 8 + k), w[k], acc0);
      acc1 = fmaf(bcast(eav, 1 * 8 + k), w[k], acc1);
      acc2 = fmaf(bcast(eav, 2 * 8 + k), w[k], acc2);
      acc3 = fmaf(bcast(eav, 3 * 8 + k), w[k], acc3);
    }
    unsigned short* ob = reinterpret_cast<unsigned short*>(ebf);
    __builtin_nontemporal_store(f2bu(fmaxf(acc0, 0.f)), ob + (size_t)i_j[0] * 64 + lane);
    __builtin_nontemporal_store(f2bu(fmaxf(acc1, 0.f)), ob + (size_t)i_j[1] * 64 + lane);
    __builtin_nontemporal_store(f2bu(fmaxf(acc2, 0.f)), ob + (size_t)i_j[2] * 64 + lane);
    __builtin_nontemporal_store(f2bu(fmaxf(acc3, 0.f)), ob + (size_t)i_j[3] * 64 + lane);
  }
}

// ---------------- edge-gated conv: CSR + LDS accumulate; epilogue = h+stats OR pool ----------------
__global__ void __launch_bounds__(256, 4) k_conv_mfma(
    const __hip_bfloat16* __restrict__ ebf,
    const float* __restrict__ We2,
    const uint32* __restrict__ htP, const unsigned short* __restrict__ htBb,
    const uint64* __restrict__ edge8,
    const uint32* __restrict__ ptr,
    float* __restrict__ hout, float* __restrict__ stats,
    const int* __restrict__ batch, float* __restrict__ gout) {
  __shared__ float lds_acc[4][NPW * 65];
  __shared__ float lds_htB[4][NPW * 65];
  __shared__ float st_s[64], st_s2[64];
  const int tid = threadIdx.x;
  const int lane = tid & 63;
  const int w = tid >> 6;
  const int m = lane & 15;
  const int kg = lane >> 4;

  int wave = blockIdx.x * 4 + w;
  int n0 = wave * NPW;
  bool validw = (n0 < N_NODESC);

  if (stats) {
    if (tid < 64) { st_s[tid] = 0.f; st_s2[tid] = 0.f; }
    __syncthreads();
  }

  // B fragments: b[t][s] -> B[k = s*32 + kg*8 + j][c = t*16 + m]
  bf16x8 b[4][2];
#pragma unroll
  for (int t = 0; t < 4; ++t)
#pragma unroll
    for (int s = 0; s < 2; ++s)
#pragma unroll
      for (int j = 0; j < 8; ++j) {
        int k = s * 32 + kg * 8 + j;
        int c = t * 16 + m;
        b[t][s][j] = (__bf16)We2[k * 64 + c];
      }

  float* acc_l = lds_acc[w];
  float* htB_l = lds_htB[w];
#pragma unroll
  for (int r = 0; r < NPW; ++r) {
    acc_l[r * 65 + lane] = 0.f;
    htB_l[r * 65 + lane] = validw ? bu2f(htBb[(size_t)(n0 + r) * 64 + lane]) : 0.f;
  }

  int e0 = validw ? (int)ptr[n0] : 0;
  int eend = validw ? (int)ptr[n0 + NPW] : 0;
  int tb0 = e0 & ~15;

  float run[4] = {0.f, 0.f, 0.f, 0.f};
  int rcur = -1;

  for (int tb = tb0; tb < eend; tb += 16) {
    // ---- loads (only VMEM in loop) ----
    const bf16x8* arow = reinterpret_cast<const bf16x8*>(ebf + (size_t)(tb + m) * 64 + kg * 8);
    bf16x8 a0 = __builtin_nontemporal_load(arow);
    bf16x8 a1 = __builtin_nontemporal_load(arow + 4);
    int rb = tb + kg * 4;
    u64x2 qa = *reinterpret_cast<const u64x2*>(edge8 + rb);
    u64x2 qb = *reinterpret_cast<const u64x2*>(edge8 + rb + 2);
    uint64 q[4] = {qa.x, qa.y, qb.x, qb.y};
    int se[4], rd[4];
    float ne[4];
#pragma unroll
    for (int j = 0; j < 4; ++j) {
      se[j] = (int)(q[j] & 0x1FFFFu);
      rd[j] = (int)((q[j] >> 17) & (NPW - 1));
      ne[j] = __uint_as_float((uint32)(q[j] >> 32));
    }
    uint4 pv[4];
#pragma unroll
    for (int j = 0; j < 4; ++j)
      pv[j] = *reinterpret_cast<const uint4*>(htP + (size_t)se[j] * 64 + m * 4);

    // ---- MFMA ----
    f32x4 acc[4];
#pragma unroll
    for (int t = 0; t < 4; ++t) {
      f32x4 z = {0.f, 0.f, 0.f, 0.f};
      acc[t] = __builtin_amdgcn_mfma_f32_16x16x32_bf16(a0, b[t][0], z, 0, 0, 0);
      acc[t] = __builtin_amdgcn_mfma_f32_16x16x32_bf16(a1, b[t][1], acc[t], 0, 0, 0);
    }

    // ---- msg + LDS run-accumulate ----
#pragma unroll
    for (int j = 0; j < 4; ++j) {
      int eidx = rb + j;
      bool valid = (eidx >= e0) && (eidx < eend);
      if (valid) {
        if (rd[j] != rcur) {
          if (rcur >= 0) {
#pragma unroll
            for (int t = 0; t < 4; ++t) {
              atomicAdd(&acc_l[rcur * 65 + t * 16 + m], run[t]);
              run[t] = 0.f;
            }
          }
          rcur = rd[j];
        }
        uint32 pd[4] = {pv[j].x, pv[j].y, pv[j].z, pv[j].w};
#pragma unroll
        for (int t = 0; t < 4; ++t) {
          int c = t * 16 + m;
          float gate = acc[t][j] + bu2f((unsigned short)(pd[t] >> 16)) + htB_l[rcur * 65 + c];
          float sig = 1.0f / (1.0f + __expf(-gate));
          run[t] = fmaf(ne[j] * bu2f((unsigned short)(pd[t] & 0xffffu)), sig, run[t]);
        }
      }
    }
  }
  if (rcur >= 0) {
#pragma unroll
    for (int t = 0; t < 4; ++t)
      atomicAdd(&acc_l[rcur * 65 + t * 16 + m], run[t]);
  }

  if (gout) {
    // ---- epilogue (last conv): fused global_add_pool, no h write ----
    if (validw) {
      int bcur = batch[n0];
      float racc = 0.f;
#pragma unroll
      for (int r = 0; r < NPW; ++r) {
        float v = fmaxf(acc_l[r * 65 + lane], 0.f);
        int bb = batch[n0 + r];
        if (bb != bcur) {
          atomicAdd(&gout[(size_t)bcur * 64 + lane], racc);
          racc = 0.f;
          bcur = bb;
        }
        racc += v;
      }
      atomicAdd(&gout[(size_t)bcur * 64 + lane], racc);
    }
  } else {
    // ---- epilogue: h = relu(acc), coalesced stores, fused column stats ----
    float s = 0.f, s2 = 0.f;
    if (validw) {
#pragma unroll
      for (int r = 0; r < NPW; ++r) {
        float v = fmaxf(acc_l[r * 65 + lane], 0.f);
        hout[(size_t)(n0 + r) * 64 + lane] = v;
        s += v; s2 += v * v;
      }
    }
    if (stats) {
      atomicAdd(&st_s[lane], s);
      atomicAdd(&st_s2[lane], s2);
      __syncthreads();
      if (tid < 64) atomicAdd(&stats[tid], st_s[tid]);
      else if (tid < 128) atomicAdd(&stats[tid], st_s2[tid - 64]);
    }
  }
}

// ---------------- classifier + log_softmax ----------------
__global__ void k_cls(const float* __restrict__ g2, const float* __restrict__ Wc,
                      const float* __restrict__ bc, float* __restrict__ out) {
  int r = blockIdx.x * blockDim.x + threadIdx.x;
  if (r >= N_GRAPHSC) return;
  float z[NCLS];
#pragma unroll
  for (int c = 0; c < NCLS; ++c) z[c] = bc[c];
  for (int k = 0; k < HDIM; ++k) {
    float v = g2[r * HDIM + k];
#pragma unroll
    for (int c = 0; c < NCLS; ++c) z[c] = fmaf(v, Wc[k * NCLS + c], z[c]);
  }
  float m = z[0];
#pragma unroll
  for (int c = 1; c < NCLS; ++c) m = fmaxf(m, z[c]);
  float ssum = 0.f;
#pragma unroll
  for (int c = 0; c < NCLS; ++c) ssum += __expf(z[c] - m);
  float l = __logf(ssum);
#pragma unroll
  for (int c = 0; c < NCLS; ++c) out[r * NCLS + c] = z[c] - m - l;
}

extern "C" void kernel_launch(void* const* d_in, const int* in_sizes, int n_in,
                              void* d_out, int out_size, void* d_ws, size_t ws_size,
                              hipStream_t stream) {
  const float* x         = (const float*)d_in[0];
  const float* edge_attr = (const float*)d_in[1];
  const int*   ei        = (const int*)d_in[2];
  const int*   batch     = (const int*)d_in[3];
  const float* bn_feat_w = (const float*)d_in[4];
  const float* bn_feat_b = (const float*)d_in[5];
  const float* Wn0       = (const float*)d_in[6];
  const float* bn0       = (const float*)d_in[7];
  const float* We0       = (const float*)d_in[8];
  const float* be0       = (const float*)d_in[9];
  const float* bns_w     = (const float*)d_in[10];
  const float* bns_b     = (const float*)d_in[11];
  const float* Wn        = (const float*)d_in[12];
  const float* Wnb       = (const float*)d_in[13];
  const float* We        = (const float*)d_in[14];
  const float* Web       = (const float*)d_in[15];
  const float* bn_fc_w   = (const float*)d_in[16];
  const float* bn_fc_b   = (const float*)d_in[17];
  const float* Wfc       = (const float*)d_in[18];
  const float* bfc       = (const float*)d_in[19];
  const float* bn_hid_w  = (const float*)d_in[20];
  const float* bn_hid_b  = (const float*)d_in[21];
  const float* Wcls      = (const float*)d_in[22];
  const float* bcls      = (const float*)d_in[23];
  float* out = (float*)d_out;
  const int* src = ei;
  const int* dst = ei + N_EDGESC;

  char* p = (char*)d_ws;
  auto carve = [&](size_t bytes) {
    char* q = p;
    p += (bytes + 255) & ~(size_t)255;
    return q;
  };
  __hip_bfloat16* ebf = (__hip_bfloat16*)carve((size_t)N_EDGESC * 64 * 2);
  float* h    = (float*)carve((size_t)N_NODESC * 64 * 4);
  uint32* htP = (uint32*)carve((size_t)N_NODESC * 64 * 4);       // {bf16 ht, bf16 htA}, col-permuted
  unsigned short* htBb = (unsigned short*)carve((size_t)N_NODESC * 64 * 2);  // linear
  unsigned short* hAb  = (unsigned short*)carve((size_t)N_NODESC * 64 * 2);
  unsigned short* hBb  = (unsigned short*)carve((size_t)N_NODESC * 64 * 2);
  float* dinv = (float*)carve((size_t)N_NODESC * 4);
  float* g    = (float*)carve((size_t)N_GRAPHSC * 64 * 4);
  float* g2   = (float*)carve((size_t)N_GRAPHSC * 64 * 4);
  float* stats= (float*)carve(4 * 128 * 4);  // 4 slots of 128 floats
  float* Wf   = (float*)carve(64 * 64 * 4);
  float* bf   = (float*)carve(64 * 4);
  uint32* degi   = (uint32*)carve((size_t)50176 * 4);
  uint32* ptr    = (uint32*)carve((size_t)50176 * 4);
  uint32* cursor = (uint32*)carve((size_t)50176 * 4);
  uint32* bsum   = (uint32*)carve(256 * 4);
  uint64* edge8 = (uint64*)carve((size_t)N_EDGESC * 8);  // packed {norm, d&7, s}

  float* st_x  = stats;            // x stats (2*32)
  float* st_h0 = stats + 128;      // h after stage0
  float* st_h1 = stats + 256;      // h after conv0
  float* st_h2 = stats + 384;      // h after conv1

  // ---- memsets: degi+ptr+cursor (contiguous), stats, g ----
  hipMemsetAsync(degi, 0, (size_t)3 * 50176 * 4, stream);
  hipMemsetAsync(stats, 0, 4 * 128 * 4, stream);
  hipMemsetAsync(g, 0, N_GRAPHSC * 64 * 4, stream);

  // ---- degree, dinv, CSR scan ----
  k_deg<<<(N_EDGESC + 255) / 256, 256, 0, stream>>>(dst, degi);
  k_scan1<<<SCAN_G, SCAN_B, 0, stream>>>(degi, ptr, bsum, dinv);
  k_scan2<<<1, 256, 0, stream>>>(bsum);
  k_scan3<<<SCAN_G, SCAN_B, 0, stream>>>(ptr, bsum);

  // ---- stage0: BN-fold, fused h0/hA/hB/relu + h-stats ----
  k_colstats<FNODE><<<256, 256, 0, stream>>>(x, N_NODESC, st_x);
  k_foldbn<FNODE, HDIM><<<1, 256, 0, stream>>>(st_x, 1.f / N_NODESC, bn_feat_w, bn_feat_b, Wn0, bn0, Wf, bf);
  k_stage0<<<512, 256, 0, stream>>>(x, N_NODESC, Wf, bf, We0, be0, We0 + 64 * 64, h, hAb, hBb, st_h0);

  // ---- fused scatter + edgeinit (sorted e, packed edge8) ----
  k_scatedge<<<1024, 256, 0, stream>>>(src, dst, edge_attr, dinv, ptr, cursor,
                                       hAb, hBb, We0 + 128 * 64, edge8, ebf);

  // ---- 3 conv rounds (epilogue: stats for next round, or pool on last) ----
  const int convBlocks = (N_NODESC / NPW + 3) / 4;  // 1563
  float* inSlot[3]  = {st_h0, st_h1, st_h2};
  float* outSlot[3] = {st_h1, st_h2, nullptr};
  for (int i = 0; i < 3; ++i) {
    const float* WeI = We + (size_t)i * 192 * 64;
    k_node3<<<512, 256, 0, stream>>>(h, N_NODESC, inSlot[i], 1.f / N_NODESC,
                                     bns_w + i * 64, bns_b + i * 64,
                                     Wn + (size_t)i * 64 * 64, Wnb + i * 64,
                                     WeI, Web + i * 64, WeI + 64 * 64, htP, htBb);
    k_conv_mfma<<<convBlocks, 256, 0, stream>>>(ebf, WeI + 128 * 64, htP, htBb, edge8,
                                                ptr, h, outSlot[i],
                                                batch, (i == 2) ? g : nullptr);
  }

  // ---- head (fused stats+fold single-block kernels) ----
  k_statsfold<HDIM, HDIM><<<1, 256, 0, stream>>>(g, N_GRAPHSC, bn_fc_w, bn_fc_b, Wfc, bfc, Wf, bf);
  k_nodemm<HDIM, true><<<128, 256, 0, stream>>>(g, N_GRAPHSC, Wf, bf, g2);
  k_statsfold<HDIM, NCLS><<<1, 256, 0, stream>>>(g2, N_GRAPHSC, bn_hid_w, bn_hid_b, Wcls, bcls, Wf, bf);
  k_cls<<<(N_GRAPHSC + 255) / 256, 256, 0, stream>>>(g2, Wf, bf, out);
}

// Round 19
// 662.935 us; speedup vs baseline: 1.0867x; 1.0867x over previous
//
#include <hip/hip_runtime.h>
#include <hip/hip_bf16.h>

#define N_NODESC 50000
#define N_EDGESC 800000
#define N_GRAPHSC 512
#define HDIM 64
#define FNODE 32
#define FEDGE 8
#define NCLS 10
#define BN_EPS 1e-5f
#define SCAN_B 256
#define SCAN_G 196  // 196*256 = 50176 >= 50000
#define NPW 8       // nodes per wave in conv (50000 -> 6250 waves)

typedef __bf16 bf16x8 __attribute__((ext_vector_type(8)));
typedef float f32x4 __attribute__((ext_vector_type(4)));
typedef unsigned long long uint64;
typedef unsigned long long u64x2 __attribute__((ext_vector_type(2)));
typedef unsigned int uint32;

static __device__ __forceinline__ float bcast(float v, int k) {
  return __uint_as_float(__builtin_amdgcn_readlane(__float_as_uint(v), k));
}
static __device__ __forceinline__ int bcast_i(int v, int k) {
  return __builtin_amdgcn_readlane(v, k);
}
static __device__ __forceinline__ unsigned short f2bu(float f) {
  __hip_bfloat16 b = __float2bfloat16(f);
  return *reinterpret_cast<unsigned short*>(&b);
}
static __device__ __forceinline__ float bu2f(unsigned short u) {
  __hip_bfloat16 b;
  *reinterpret_cast<unsigned short*>(&b) = u;
  return __bfloat162float(b);
}

// ---------------- degree ----------------
__global__ void k_deg(const int* __restrict__ dst, uint32* __restrict__ degi) {
  int e = blockIdx.x * blockDim.x + threadIdx.x;
  if (e < N_EDGESC) atomicAdd(&degi[dst[e]], 1u);
}

// ---------------- scan1 (+ fused dinv) ----------------
__global__ void k_scan1(const uint32* __restrict__ degi, uint32* __restrict__ ptr,
                        uint32* __restrict__ bsum, float* __restrict__ dinv) {
  __shared__ uint32 s[SCAN_B];
  int t = threadIdx.x;
  int i = blockIdx.x * SCAN_B + t;
  uint32 v = (i < N_NODESC) ? degi[i] : 0u;
  if (i < N_NODESC) dinv[i] = rsqrtf(fmaxf((float)v, 1.0f));
  s[t] = v; __syncthreads();
  for (int off = 1; off < SCAN_B; off <<= 1) {
    uint32 x = (t >= off) ? s[t - off] : 0u; __syncthreads();
    s[t] += x; __syncthreads();
  }
  if (i < N_NODESC) ptr[i] = s[t] - v;  // exclusive local scan
  if (t == SCAN_B - 1) bsum[blockIdx.x] = s[t];
}

__global__ void k_scan2(uint32* __restrict__ bsum) {
  __shared__ uint32 s[256];
  int t = threadIdx.x;
  uint32 v = (t < SCAN_G) ? bsum[t] : 0u;
  s[t] = v; __syncthreads();
  for (int off = 1; off < 256; off <<= 1) {
    uint32 x = (t >= off) ? s[t - off] : 0u; __syncthreads();
    s[t] += x; __syncthreads();
  }
  if (t < SCAN_G) bsum[t] = s[t] - v;  // exclusive
}

__global__ void k_scan3(uint32* __restrict__ ptr, const uint32* __restrict__ bsum) {
  int i = blockIdx.x * SCAN_B + threadIdx.x;
  if (i < N_NODESC) ptr[i] += bsum[blockIdx.x];
  if (blockIdx.x == 0 && threadIdx.x == 0) ptr[N_NODESC] = N_EDGESC;  // CSR sentinel
}

// ---------------- column stats (sum, sumsq) into a slot ----------------
template <int C>
__global__ void k_colstats(const float* __restrict__ in, int nrows, float* __restrict__ stats) {
  const int RPB = 256 / C;
  int tid = threadIdx.x;
  int col = tid % C;
  int rowOff = tid / C;
  float s = 0.f, s2 = 0.f;
  for (int r = blockIdx.x * RPB + rowOff; r < nrows; r += gridDim.x * RPB) {
    float v = in[r * C + col];
    s += v; s2 += v * v;
  }
  __shared__ float ls[256], ls2[256];
  ls[tid] = s; ls2[tid] = s2;
  __syncthreads();
  for (int off = 128; off >= C; off >>= 1) {
    if (tid < off) { ls[tid] += ls[tid + off]; ls2[tid] += ls2[tid + off]; }
    __syncthreads();
  }
  if (tid < C) {
    atomicAdd(&stats[tid], ls[tid]);
    atomicAdd(&stats[C + tid], ls2[tid]);
  }
}

// ---------------- fold BN into weights (from precomputed stats slot) ----------------
template <int CIN, int COUT>
__global__ void k_foldbn(const float* __restrict__ stats, float invN,
                         const float* __restrict__ bnw, const float* __restrict__ bnb,
                         const float* __restrict__ W, const float* __restrict__ bias,
                         float* __restrict__ Wf, float* __restrict__ bf) {
  __shared__ float a[CIN], sh[CIN];
  int tid = threadIdx.x;
  if (tid < CIN) {
    float m = stats[tid] * invN;
    float v = stats[CIN + tid] * invN - m * m;
    float inv = rsqrtf(v + BN_EPS);
    float aa = bnw[tid] * inv;
    a[tid] = aa;
    sh[tid] = bnb[tid] - m * aa;
  }
  __syncthreads();
  for (int i = tid; i < CIN * COUT; i += 256) {
    int r = i / COUT;
    Wf[i] = a[r] * W[i];
  }
  if (tid < COUT) {
    float acc = bias ? bias[tid] : 0.f;
    for (int r = 0; r < CIN; ++r) acc += sh[r] * W[r * COUT + tid];
    bf[tid] = acc;
  }
}

// ---------------- head matmul: out[N,64] = in @ W + bias, relu ----------------
template <int K, bool RELU>
__global__ void k_nodemm(const float* __restrict__ in, int nrows,
                         const float* __restrict__ W, const float* __restrict__ bias,
                         float* __restrict__ out) {
  int tid = threadIdx.x;
  int lane = tid & 63;
  float w[K];
#pragma unroll
  for (int k = 0; k < K; ++k) w[k] = W[k * 64 + lane];
  float bv = bias ? bias[lane] : 0.f;
  int wave = (blockIdx.x * blockDim.x + tid) >> 6;
  int nwaves = (gridDim.x * blockDim.x) >> 6;
  for (int r = wave; r < nrows; r += nwaves) {
    float rv = (lane < K) ? in[(size_t)r * K + lane] : 0.f;
    float acc = bv;
#pragma unroll
    for (int k = 0; k < K; ++k) acc = fmaf(bcast(rv, k), w[k], acc);
    if (RELU) acc = fmaxf(acc, 0.f);
    out[(size_t)r * 64 + lane] = acc;
  }
}

// ---------------- fused stage0: h0/hA/hB/relu + fused h-stats ----------------
__global__ void __launch_bounds__(256, 2) k_stage0(
    const float* __restrict__ x, int nrows,
    const float* __restrict__ Wf, const float* __restrict__ bfv,
    const float* __restrict__ WA, const float* __restrict__ bA,
    const float* __restrict__ WB,
    float* __restrict__ h, unsigned short* __restrict__ hAb,
    unsigned short* __restrict__ hBb, float* __restrict__ stats) {
  __shared__ float st_s[64], st_s2[64];
  int tid = threadIdx.x;
  int lane = tid & 63;
  if (tid < 64) { st_s[tid] = 0.f; st_s2[tid] = 0.f; }
  __syncthreads();
  float w0[FNODE], wA[64], wB[64];
#pragma unroll
  for (int k = 0; k < FNODE; ++k) w0[k] = Wf[k * 64 + lane];
#pragma unroll
  for (int k = 0; k < 64; ++k) wA[k] = WA[k * 64 + lane];
#pragma unroll
  for (int k = 0; k < 64; ++k) wB[k] = WB[k * 64 + lane];
  float b0 = bfv[lane];
  float b2 = bA[lane];
  int wave = (blockIdx.x * blockDim.x + tid) >> 6;
  int nwaves = (gridDim.x * blockDim.x) >> 6;
  float s = 0.f, s2 = 0.f;
  for (int r = wave; r < nrows; r += nwaves) {
    float xv = (lane < FNODE) ? x[(size_t)r * FNODE + lane] : 0.f;
    float t0 = b0;
#pragma unroll
    for (int k = 0; k < FNODE; ++k) t0 = fmaf(bcast(xv, k), w0[k], t0);  // h0 (pre-relu)
    float aA = b2, aB = 0.f;
#pragma unroll
    for (int k = 0; k < 64; ++k) {
      float tb = bcast(t0, k);
      aA = fmaf(tb, wA[k], aA);
      aB = fmaf(tb, wB[k], aB);
    }
    float hv = fmaxf(t0, 0.f);
    h[(size_t)r * 64 + lane] = hv;
    s += hv; s2 += hv * hv;
    hAb[(size_t)r * 64 + lane] = f2bu(aA);
    hBb[(size_t)r * 64 + lane] = f2bu(aB);
  }
  atomicAdd(&st_s[lane], s);
  atomicAdd(&st_s2[lane], s2);
  __syncthreads();
  if (tid < 64) atomicAdd(&stats[tid], st_s[tid]);
  else if (tid < 128) atomicAdd(&stats[tid], st_s2[tid - 64]);
}

// ---------------- fused per-conv node prep (inline BN fold): ht, htA, htB ----------------
// htP col-PERMUTED (c' = (c&15)*4 + (c>>4)); htBb LINEAR.
__global__ void __launch_bounds__(256, 2) k_node3(
    const float* __restrict__ h, int nrows,
    const float* __restrict__ stats, float invN,
    const float* __restrict__ bnw, const float* __restrict__ bnb,
    const float* __restrict__ Wn_i, const float* __restrict__ Wnb_i,
    const float* __restrict__ WA, const float* __restrict__ Wab,
    const float* __restrict__ WB,
    uint32* __restrict__ htP, unsigned short* __restrict__ htBb) {
  __shared__ float a_s[64], sh_s[64];
  int tid = threadIdx.x;
  int lane = tid & 63;
  if (tid < 64) {
    float m = stats[tid] * invN;
    float v = stats[64 + tid] * invN - m * m;
    float inv = rsqrtf(v + BN_EPS);
    float aa = bnw[tid] * inv;
    a_s[tid] = aa;
    sh_s[tid] = bnb[tid] - m * aa;
  }
  __syncthreads();
  float w1[64], w2[64], w3[64];
  float b1 = Wnb_i[lane];
#pragma unroll
  for (int k = 0; k < 64; ++k) {
    float raw = Wn_i[k * 64 + lane];
    w1[k] = a_s[k] * raw;
    b1 = fmaf(sh_s[k], raw, b1);
  }
#pragma unroll
  for (int k = 0; k < 64; ++k) w2[k] = WA[k * 64 + lane];
#pragma unroll
  for (int k = 0; k < 64; ++k) w3[k] = WB[k * 64 + lane];
  float b2 = Wab[lane];
  int cperm = (lane & 15) * 4 + (lane >> 4);
  int wave = (blockIdx.x * blockDim.x + tid) >> 6;
  int nwaves = (gridDim.x * blockDim.x) >> 6;
  for (int r = wave; r < nrows; r += nwaves) {
    float hv = h[(size_t)r * 64 + lane];
    float t1 = b1;
#pragma unroll
    for (int k = 0; k < 64; ++k) t1 = fmaf(bcast(hv, k), w1[k], t1);  // ht
    float t2 = b2;
    float t3 = 0.f;
#pragma unroll
    for (int k = 0; k < 64; ++k) {
      float tb = bcast(t1, k);
      t2 = fmaf(tb, w2[k], t2);  // htA (+Web)
      t3 = fmaf(tb, w3[k], t3);  // htB
    }
    htP[(size_t)r * 64 + cperm] = ((uint32)f2bu(t2) << 16) | (uint32)f2bu(t1);
    htBb[(size_t)r * 64 + lane] = f2bu(t3);
  }
}

// ---------------- fused scatter + edge-init (8-byte packed edge record) ----------------
// rec u64 = norm_f32 << 32 | (d&7) << 17 | s
__global__ void k_scatedge(
    const int* __restrict__ src, const int* __restrict__ dst,
    const float* __restrict__ ea, const float* __restrict__ dinv,
    const uint32* __restrict__ ptr, uint32* __restrict__ cursor,
    const unsigned short* __restrict__ hAb, const unsigned short* __restrict__ hBb,
    const float* __restrict__ Wc,
    uint64* __restrict__ edge8,
    __hip_bfloat16* __restrict__ ebf) {
  int tid = threadIdx.x;
  int lane = tid & 63;
  float w[FEDGE];
#pragma unroll
  for (int k = 0; k < FEDGE; ++k) w[k] = Wc[k * 64 + lane];
  int wave = (blockIdx.x * blockDim.x + tid) >> 6;
  int nwaves = (gridDim.x * blockDim.x) >> 6;
  const int nquads = N_EDGESC / 4;
  int per = (nquads + nwaves - 1) / nwaves;
  int p0 = wave * per;
  int p1 = min(p0 + per, nquads);
  for (int pr = p0; pr < p1; ++pr) {
    int e = 4 * pr;
    // lanes 0..3 own one edge each
    int sv = (lane < 4) ? src[e + lane] : 0;
    int dv = (lane < 4) ? dst[e + lane] : 0;
    int s_j[4], d_j[4];
#pragma unroll
    for (int j = 0; j < 4; ++j) { s_j[j] = bcast_i(sv, j); d_j[j] = bcast_i(dv, j); }
    uint32 idx_l = 0;
    if (lane < 4) {
      uint32 rk = atomicAdd(&cursor[dv], 1u);
      idx_l = ptr[dv] + rk;
      float nf = dinv[sv] * dinv[dv];
      uint64 rec = ((uint64)__float_as_uint(nf) << 32) |
                   ((uint64)(dv & (NPW - 1)) << 17) | (uint64)(uint32)sv;
      __builtin_nontemporal_store(rec, edge8 + idx_l);
    }
    int i_j[4];
#pragma unroll
    for (int j = 0; j < 4; ++j) i_j[j] = bcast_i((int)idx_l, j);
    // ea for 4 edges: 32 contiguous floats
    float eav = (lane < 32) ? ea[(size_t)e * FEDGE + lane] : 0.f;
    // row gathers
    unsigned short a0 = hAb[(size_t)s_j[0] * 64 + lane], b0 = hBb[(size_t)d_j[0] * 64 + lane];
    unsigned short a1 = hAb[(size_t)s_j[1] * 64 + lane], b1 = hBb[(size_t)d_j[1] * 64 + lane];
    unsigned short a2 = hAb[(size_t)s_j[2] * 64 + lane], b2 = hBb[(size_t)d_j[2] * 64 + lane];
    unsigned short a3 = hAb[(size_t)s_j[3] * 64 + lane], b3 = hBb[(size_t)d_j[3] * 64 + lane];
    float acc0 = bu2f(a0) + bu2f(b0);
    float acc1 = bu2f(a1) + bu2f(b1);
    float acc2 = bu2f(a2) + bu2f(b2);
    float acc3 = bu2f(a3) + bu2f(b3);
#pragma unroll
    for (int k = 0; k < FEDGE; ++k) {
      acc0 = fmaf(bcast(eav, 0 * 8 + k), w[k], acc0);
      acc1 = fmaf(bcast(eav, 1 * 8 + k), w[k], acc1);
      acc2 = fmaf(bcast(eav, 2 * 8 + k), w[k], acc2);
      acc3 = fmaf(bcast(eav, 3 * 8 + k), w[k], acc3);
    }
    unsigned short* ob = reinterpret_cast<unsigned short*>(ebf);
    __builtin_nontemporal_store(f2bu(fmaxf(acc0, 0.f)), ob + (size_t)i_j[0] * 64 + lane);
    __builtin_nontemporal_store(f2bu(fmaxf(acc1, 0.f)), ob + (size_t)i_j[1] * 64 + lane);
    __builtin_nontemporal_store(f2bu(fmaxf(acc2, 0.f)), ob + (size_t)i_j[2] * 64 + lane);
    __builtin_nontemporal_store(f2bu(fmaxf(acc3, 0.f)), ob + (size_t)i_j[3] * 64 + lane);
  }
}

// ---------------- edge-gated conv: CSR + LDS accumulate; epilogue = h+stats OR pool ----------------
__global__ void __launch_bounds__(256, 4) k_conv_mfma(
    const __hip_bfloat16* __restrict__ ebf,
    const float* __restrict__ We2,
    const uint32* __restrict__ htP, const unsigned short* __restrict__ htBb,
    const uint64* __restrict__ edge8,
    const uint32* __restrict__ ptr,
    float* __restrict__ hout, float* __restrict__ stats,
    const int* __restrict__ batch, float* __restrict__ gout) {
  __shared__ float lds_acc[4][NPW * 65];
  __shared__ float lds_htB[4][NPW * 65];
  __shared__ float st_s[64], st_s2[64];
  const int tid = threadIdx.x;
  const int lane = tid & 63;
  const int w = tid >> 6;
  const int m = lane & 15;
  const int kg = lane >> 4;

  int wave = blockIdx.x * 4 + w;
  int n0 = wave * NPW;
  bool validw = (n0 < N_NODESC);

  if (stats) {
    if (tid < 64) { st_s[tid] = 0.f; st_s2[tid] = 0.f; }
    __syncthreads();
  }

  // B fragments: b[t][s] -> B[k = s*32 + kg*8 + j][c = t*16 + m]
  bf16x8 b[4][2];
#pragma unroll
  for (int t = 0; t < 4; ++t)
#pragma unroll
    for (int s = 0; s < 2; ++s)
#pragma unroll
      for (int j = 0; j < 8; ++j) {
        int k = s * 32 + kg * 8 + j;
        int c = t * 16 + m;
        b[t][s][j] = (__bf16)We2[k * 64 + c];
      }

  float* acc_l = lds_acc[w];
  float* htB_l = lds_htB[w];
#pragma unroll
  for (int r = 0; r < NPW; ++r) {
    acc_l[r * 65 + lane] = 0.f;
    htB_l[r * 65 + lane] = validw ? bu2f(htBb[(size_t)(n0 + r) * 64 + lane]) : 0.f;
  }

  int e0 = validw ? (int)ptr[n0] : 0;
  int eend = validw ? (int)ptr[n0 + NPW] : 0;
  int tb0 = e0 & ~15;

  float run[4] = {0.f, 0.f, 0.f, 0.f};
  int rcur = -1;

  for (int tb = tb0; tb < eend; tb += 16) {
    // ---- loads (only VMEM in loop) ----
    const bf16x8* arow = reinterpret_cast<const bf16x8*>(ebf + (size_t)(tb + m) * 64 + kg * 8);
    bf16x8 a0 = __builtin_nontemporal_load(arow);
    bf16x8 a1 = __builtin_nontemporal_load(arow + 4);
    int rb = tb + kg * 4;
    u64x2 qa = *reinterpret_cast<const u64x2*>(edge8 + rb);
    u64x2 qb = *reinterpret_cast<const u64x2*>(edge8 + rb + 2);
    uint64 q[4] = {qa.x, qa.y, qb.x, qb.y};
    int se[4], rd[4];
    float ne[4];
#pragma unroll
    for (int j = 0; j < 4; ++j) {
      se[j] = (int)(q[j] & 0x1FFFFu);
      rd[j] = (int)((q[j] >> 17) & (NPW - 1));
      ne[j] = __uint_as_float((uint32)(q[j] >> 32));
    }
    uint4 pv[4];
#pragma unroll
    for (int j = 0; j < 4; ++j)
      pv[j] = *reinterpret_cast<const uint4*>(htP + (size_t)se[j] * 64 + m * 4);

    // ---- MFMA ----
    f32x4 acc[4];
#pragma unroll
    for (int t = 0; t < 4; ++t) {
      f32x4 z = {0.f, 0.f, 0.f, 0.f};
      acc[t] = __builtin_amdgcn_mfma_f32_16x16x32_bf16(a0, b[t][0], z, 0, 0, 0);
      acc[t] = __builtin_amdgcn_mfma_f32_16x16x32_bf16(a1, b[t][1], acc[t], 0, 0, 0);
    }

    // ---- msg + LDS run-accumulate ----
#pragma unroll
    for (int j = 0; j < 4; ++j) {
      int eidx = rb + j;
      bool valid = (eidx >= e0) && (eidx < eend);
      if (valid) {
        if (rd[j] != rcur) {
          if (rcur >= 0) {
#pragma unroll
            for (int t = 0; t < 4; ++t) {
              atomicAdd(&acc_l[rcur * 65 + t * 16 + m], run[t]);
              run[t] = 0.f;
            }
          }
          rcur = rd[j];
        }
        uint32 pd[4] = {pv[j].x, pv[j].y, pv[j].z, pv[j].w};
#pragma unroll
        for (int t = 0; t < 4; ++t) {
          int c = t * 16 + m;
          float gate = acc[t][j] + bu2f((unsigned short)(pd[t] >> 16)) + htB_l[rcur * 65 + c];
          float sig = 1.0f / (1.0f + __expf(-gate));
          run[t] = fmaf(ne[j] * bu2f((unsigned short)(pd[t] & 0xffffu)), sig, run[t]);
        }
      }
    }
  }
  if (rcur >= 0) {
#pragma unroll
    for (int t = 0; t < 4; ++t)
      atomicAdd(&acc_l[rcur * 65 + t * 16 + m], run[t]);
  }

  if (gout) {
    // ---- epilogue (last conv): fused global_add_pool, no h write ----
    if (validw) {
      int bcur = batch[n0];
      float racc = 0.f;
#pragma unroll
      for (int r = 0; r < NPW; ++r) {
        float v = fmaxf(acc_l[r * 65 + lane], 0.f);
        int bb = batch[n0 + r];
        if (bb != bcur) {
          atomicAdd(&gout[(size_t)bcur * 64 + lane], racc);
          racc = 0.f;
          bcur = bb;
        }
        racc += v;
      }
      atomicAdd(&gout[(size_t)bcur * 64 + lane], racc);
    }
  } else {
    // ---- epilogue: h = relu(acc), coalesced stores, fused column stats ----
    float s = 0.f, s2 = 0.f;
    if (validw) {
#pragma unroll
      for (int r = 0; r < NPW; ++r) {
        float v = fmaxf(acc_l[r * 65 + lane], 0.f);
        hout[(size_t)(n0 + r) * 64 + lane] = v;
        s += v; s2 += v * v;
      }
    }
    if (stats) {
      atomicAdd(&st_s[lane], s);
      atomicAdd(&st_s2[lane], s2);
      __syncthreads();
      if (tid < 64) atomicAdd(&stats[tid], st_s[tid]);
      else if (tid < 128) atomicAdd(&stats[tid], st_s2[tid - 64]);
    }
  }
}

// ---------------- classifier + log_softmax ----------------
__global__ void k_cls(const float* __restrict__ g2, const float* __restrict__ Wc,
                      const float* __restrict__ bc, float* __restrict__ out) {
  int r = blockIdx.x * blockDim.x + threadIdx.x;
  if (r >= N_GRAPHSC) return;
  float z[NCLS];
#pragma unroll
  for (int c = 0; c < NCLS; ++c) z[c] = bc[c];
  for (int k = 0; k < HDIM; ++k) {
    float v = g2[r * HDIM + k];
#pragma unroll
    for (int c = 0; c < NCLS; ++c) z[c] = fmaf(v, Wc[k * NCLS + c], z[c]);
  }
  float m = z[0];
#pragma unroll
  for (int c = 1; c < NCLS; ++c) m = fmaxf(m, z[c]);
  float ssum = 0.f;
#pragma unroll
  for (int c = 0; c < NCLS; ++c) ssum += __expf(z[c] - m);
  float l = __logf(ssum);
#pragma unroll
  for (int c = 0; c < NCLS; ++c) out[r * NCLS + c] = z[c] - m - l;
}

extern "C" void kernel_launch(void* const* d_in, const int* in_sizes, int n_in,
                              void* d_out, int out_size, void* d_ws, size_t ws_size,
                              hipStream_t stream) {
  const float* x         = (const float*)d_in[0];
  const float* edge_attr = (const float*)d_in[1];
  const int*   ei        = (const int*)d_in[2];
  const int*   batch     = (const int*)d_in[3];
  const float* bn_feat_w = (const float*)d_in[4];
  const float* bn_feat_b = (const float*)d_in[5];
  const float* Wn0       = (const float*)d_in[6];
  const float* bn0       = (const float*)d_in[7];
  const float* We0       = (const float*)d_in[8];
  const float* be0       = (const float*)d_in[9];
  const float* bns_w     = (const float*)d_in[10];
  const float* bns_b     = (const float*)d_in[11];
  const float* Wn        = (const float*)d_in[12];
  const float* Wnb       = (const float*)d_in[13];
  const float* We        = (const float*)d_in[14];
  const float* Web       = (const float*)d_in[15];
  const float* bn_fc_w   = (const float*)d_in[16];
  const float* bn_fc_b   = (const float*)d_in[17];
  const float* Wfc       = (const float*)d_in[18];
  const float* bfc       = (const float*)d_in[19];
  const float* bn_hid_w  = (const float*)d_in[20];
  const float* bn_hid_b  = (const float*)d_in[21];
  const float* Wcls      = (const float*)d_in[22];
  const float* bcls      = (const float*)d_in[23];
  float* out = (float*)d_out;
  const int* src = ei;
  const int* dst = ei + N_EDGESC;

  char* p = (char*)d_ws;
  auto carve = [&](size_t bytes) {
    char* q = p;
    p += (bytes + 255) & ~(size_t)255;
    return q;
  };
  __hip_bfloat16* ebf = (__hip_bfloat16*)carve((size_t)N_EDGESC * 64 * 2);
  float* h    = (float*)carve((size_t)N_NODESC * 64 * 4);
  uint32* htP = (uint32*)carve((size_t)N_NODESC * 64 * 4);       // {bf16 ht, bf16 htA}, col-permuted
  unsigned short* htBb = (unsigned short*)carve((size_t)N_NODESC * 64 * 2);  // linear
  unsigned short* hAb  = (unsigned short*)carve((size_t)N_NODESC * 64 * 2);
  unsigned short* hBb  = (unsigned short*)carve((size_t)N_NODESC * 64 * 2);
  float* dinv = (float*)carve((size_t)N_NODESC * 4);
  float* g    = (float*)carve((size_t)N_GRAPHSC * 64 * 4);
  float* g2   = (float*)carve((size_t)N_GRAPHSC * 64 * 4);
  float* stats= (float*)carve(6 * 128 * 4);  // 6 slots of 128 floats
  float* Wf   = (float*)carve(64 * 64 * 4);
  float* bf   = (float*)carve(64 * 4);
  uint32* degi   = (uint32*)carve((size_t)50176 * 4);
  uint32* ptr    = (uint32*)carve((size_t)50176 * 4);
  uint32* cursor = (uint32*)carve((size_t)50176 * 4);
  uint32* bsum   = (uint32*)carve(256 * 4);
  uint64* edge8 = (uint64*)carve((size_t)N_EDGESC * 8);  // packed {norm, d&7, s}

  float* st_x  = stats;            // x stats (2*32)
  float* st_h0 = stats + 128;      // h after stage0
  float* st_h1 = stats + 256;      // h after conv0
  float* st_h2 = stats + 384;      // h after conv1
  float* st_g  = stats + 512;      // pooled g
  float* st_g2 = stats + 640;      // g2

  // ---- memsets: degi+ptr+cursor (contiguous), stats, g ----
  hipMemsetAsync(degi, 0, (size_t)3 * 50176 * 4, stream);
  hipMemsetAsync(stats, 0, 6 * 128 * 4, stream);
  hipMemsetAsync(g, 0, N_GRAPHSC * 64 * 4, stream);

  // ---- degree, dinv, CSR scan ----
  k_deg<<<(N_EDGESC + 255) / 256, 256, 0, stream>>>(dst, degi);
  k_scan1<<<SCAN_G, SCAN_B, 0, stream>>>(degi, ptr, bsum, dinv);
  k_scan2<<<1, 256, 0, stream>>>(bsum);
  k_scan3<<<SCAN_G, SCAN_B, 0, stream>>>(ptr, bsum);

  // ---- stage0: BN-fold, fused h0/hA/hB/relu + h-stats ----
  k_colstats<FNODE><<<256, 256, 0, stream>>>(x, N_NODESC, st_x);
  k_foldbn<FNODE, HDIM><<<1, 256, 0, stream>>>(st_x, 1.f / N_NODESC, bn_feat_w, bn_feat_b, Wn0, bn0, Wf, bf);
  k_stage0<<<512, 256, 0, stream>>>(x, N_NODESC, Wf, bf, We0, be0, We0 + 64 * 64, h, hAb, hBb, st_h0);

  // ---- fused scatter + edgeinit (sorted e, packed edge8) ----
  k_scatedge<<<1024, 256, 0, stream>>>(src, dst, edge_attr, dinv, ptr, cursor,
                                       hAb, hBb, We0 + 128 * 64, edge8, ebf);

  // ---- 3 conv rounds (epilogue: stats for next round, or pool on last) ----
  const int convBlocks = (N_NODESC / NPW + 3) / 4;  // 1563
  float* inSlot[3]  = {st_h0, st_h1, st_h2};
  float* outSlot[3] = {st_h1, st_h2, nullptr};
  for (int i = 0; i < 3; ++i) {
    const float* WeI = We + (size_t)i * 192 * 64;
    k_node3<<<512, 256, 0, stream>>>(h, N_NODESC, inSlot[i], 1.f / N_NODESC,
                                     bns_w + i * 64, bns_b + i * 64,
                                     Wn + (size_t)i * 64 * 64, Wnb + i * 64,
                                     WeI, Web + i * 64, WeI + 64 * 64, htP, htBb);
    k_conv_mfma<<<convBlocks, 256, 0, stream>>>(ebf, WeI + 128 * 64, htP, htBb, edge8,
                                                ptr, h, outSlot[i],
                                                batch, (i == 2) ? g : nullptr);
  }

  // ---- head (multi-block stats + fold) ----
  k_colstats<HDIM><<<32, 256, 0, stream>>>(g, N_GRAPHSC, st_g);
  k_foldbn<HDIM, HDIM><<<1, 256, 0, stream>>>(st_g, 1.f / N_GRAPHSC, bn_fc_w, bn_fc_b, Wfc, bfc, Wf, bf);
  k_nodemm<HDIM, true><<<128, 256, 0, stream>>>(g, N_GRAPHSC, Wf, bf, g2);
  k_colstats<HDIM><<<32, 256, 0, stream>>>(g2, N_GRAPHSC, st_g2);
  k_foldbn<HDIM, NCLS><<<1, 256, 0, stream>>>(st_g2, 1.f / N_GRAPHSC, bn_hid_w, bn_hid_b, Wcls, bcls, Wf, bf);
  k_cls<<<(N_GRAPHSC + 255) / 256, 256, 0, stream>>>(g2, Wf, bf, out);
}